// Round 13
// baseline (429.051 us; speedup 1.0000x reference)
//
#include <hip/hip_runtime.h>

// Problem constants (SpeakerAwareCTC): B=16, T=1000, D=512, V=5000, U=64, S=2U+1=129
#define NB 16
#define NT 1000
#define ND 512
#define NV 5000
#define NVP 5120          // WT padded rows (zeros beyond 5000)
#define NU 64
#define NLL 66            // ll row stride (u-major rows, 65 used)
#define NWG 72            // Wg padded u-rows
#define NM (NB * NT)      // 16000 flattened rows
#define NCH 40            // N-chunks of 128 cols

typedef short short8v __attribute__((ext_vector_type(8)));
typedef float float4v __attribute__((ext_vector_type(4)));

#define NEGINF (-__builtin_inff())
#define SENTL  (-1.0e30f)   // finite "-inf"
#define LOG2E 1.4426950408889634f
#define LN2F  0.6931471805599453f
// reference sentinel: -2001 + logf(expf(1)-1) = -2000.4586751f (natural), base-2:
#define SENT2 (-2000.4586751f * LOG2E)

__device__ __forceinline__ float fexp2(float x) { return __builtin_amdgcn_exp2f(x); }
__device__ __forceinline__ float flog2(float x) { return __builtin_amdgcn_logf(x); }

__device__ __forceinline__ float dpp_shr1(float x) {  // lane i <- lane i-1
  int xi = __builtin_bit_cast(int, x);
  int r = __builtin_amdgcn_update_dpp(xi, xi, 0x138, 0xf, 0xf, false);
  return __builtin_bit_cast(float, r);
}
__device__ __forceinline__ float dpp_shl1(float x) {  // lane i <- lane i+1
  int xi = __builtin_bit_cast(int, x);
  int r = __builtin_amdgcn_update_dpp(xi, xi, 0x130, 0xf, 0xf, false);
  return __builtin_bit_cast(float, r);
}

__device__ __forceinline__ short f2bf(float x) {
  unsigned int u = __builtin_bit_cast(unsigned int, x);
  unsigned int r = (u + 0x7fffu + ((u >> 16) & 1u)) >> 16;
  return (short)(unsigned short)r;
}
__device__ __forceinline__ float bf2f(short h) {
  unsigned int u = ((unsigned int)(unsigned short)h) << 16;
  return __builtin_bit_cast(float, u);
}

__device__ __forceinline__ void g2lds16(const short* g, short* l) {
  __builtin_amdgcn_global_load_lds(
      (const __attribute__((address_space(1))) void*)g,
      (__attribute__((address_space(3))) void*)l, 16, 0, 0);
}

__device__ __forceinline__ float lae2s(float a, float b) {
  float m = fmaxf(a, b);
  return m + flog2(fexp2(a - m) + fexp2(b - m));
}
__device__ __forceinline__ float lae3s(float a, float b, float c) {
  float m = fmaxf(fmaxf(a, b), c);
  return m + flog2(fexp2(a - m) + fexp2(b - m) + fexp2(c - m));
}
// faithful log_substraction_exp (normalized domain, finite sentinels):
// mask2 (finite a, "-inf" b) -> a; both "-inf" -> SENTL; inf tmp -> SENT2.
__device__ __forceinline__ float lsub2(float a, float b) {
  if (b < -1.0e29f) return (a < -1.0e29f) ? SENTL : a;
  float tmp = b + flog2(fexp2(a - b) - 1.0f);
  if (__builtin_isinf(tmp)) tmp = SENT2;
  return tmp;   // NaN (a<b rounding) passes through -> masked in k_loss
}

// ------ kernel 1: fused converts: hs->bf16 swizzled | W->WT/WTlo ----------
__global__ __launch_bounds__(256) void k_cvt(const float* __restrict__ hs,
                                             const float* __restrict__ W,
                                             short* __restrict__ hsb,
                                             short* __restrict__ WT,
                                             short* __restrict__ WTlo,
                                             float* __restrict__ outv) {
  __shared__ short tileH[64 * 72];
  __shared__ short tileL[64 * 72];
  if (blockIdx.x < 4000) {
    if (blockIdx.x == 0 && threadIdx.x == 0) outv[0] = 0.0f;
    size_t i = (size_t)blockIdx.x * 256 + threadIdx.x;
    const float4* p = (const float4*)hs + i * 2;
    float4 v0 = p[0], v1 = p[1];
    short8v r;
    r[0] = f2bf(v0.x); r[1] = f2bf(v0.y); r[2] = f2bf(v0.z); r[3] = f2bf(v0.w);
    r[4] = f2bf(v1.x); r[5] = f2bf(v1.y); r[6] = f2bf(v1.z); r[7] = f2bf(v1.w);
    int row = (int)(i >> 6);
    int g = (int)(i & 63);
    int gs = (g & ~7) | ((g & 7) ^ (row & 7));
    *(short8v*)(hsb + (size_t)row * ND + gs * 8) = r;
    return;
  }
  int bx = blockIdx.x - 4000;
  int n0 = (bx % 80) * 64, k0 = (bx / 80) * 64;
  int tid = threadIdx.x;
  int kr = tid >> 2, part = tid & 3;
  const float* src = W + (size_t)(k0 + kr) * NV + n0 + part * 16;
#pragma unroll
  for (int jj = 0; jj < 4; ++jj) {
    int c = n0 + part * 16 + jj * 4;
    float4 v;
    if (c + 3 < NV) {
      v = *(const float4*)(src + jj * 4);
    } else {
      v.x = (c + 0 < NV) ? src[jj * 4 + 0] : 0.f;
      v.y = (c + 1 < NV) ? src[jj * 4 + 1] : 0.f;
      v.z = (c + 2 < NV) ? src[jj * 4 + 2] : 0.f;
      v.w = (c + 3 < NV) ? src[jj * 4 + 3] : 0.f;
    }
    int base = kr * 72 + part * 16 + jj * 4;
    float vv[4] = {v.x, v.y, v.z, v.w};
#pragma unroll
    for (int q = 0; q < 4; ++q) {
      short h = f2bf(vv[q]);
      tileH[base + q] = h;
      tileL[base + q] = f2bf(vv[q] - bf2f(h));
    }
  }
  __syncthreads();
  int n = tid & 63, kq = tid >> 6;
  int nn = n0 + n;
  if (nn < NVP) {
#pragma unroll
    for (int half = 0; half < 2; ++half) {
      short8v vh, vl;
#pragma unroll
      for (int jj = 0; jj < 8; ++jj) {
        vh[jj] = tileH[(kq * 16 + half * 8 + jj) * 72 + n];
        vl[jj] = tileL[(kq * 16 + half * 8 + jj) * 72 + n];
      }
      int g = (k0 >> 3) + kq * 2 + half;
      int gs = (g & ~7) | ((g & 7) ^ (nn & 7));
      *(short8v*)(WT + (size_t)nn * ND + gs * 8) = vh;
      *(short8v*)(WTlo + (size_t)nn * ND + gs * 8) = vl;
    }
  }
}

// -------- kernel 2: gather Wg_hi/lo[b][u][k] from WT/WTlo rows -------------
__global__ __launch_bounds__(64) void k_gather2(const short* __restrict__ WT,
                                                const short* __restrict__ WTlo,
                                                const int* __restrict__ ys,
                                                short* __restrict__ Wg_hi,
                                                short* __restrict__ Wg_lo) {
  int u = blockIdx.x, b = blockIdx.y, t = threadIdx.x;
  short8v hi = {0,0,0,0,0,0,0,0}, lo = {0,0,0,0,0,0,0,0};
  if (u < NU + 1) {
    int lab = (u == 0) ? 0 : ys[b * NU + u - 1];
    int ps = (t & ~7) | ((t & 7) ^ (lab & 7));
    hi = *(const short8v*)(WT + (size_t)lab * ND + ps * 8);
    lo = *(const short8v*)(WTlo + (size_t)lab * ND + ps * 8);
  }
  int q = (t & ~7) | ((t & 7) ^ (u & 7));
  size_t base = ((size_t)(b * NWG + u)) * ND + q * 8;
  *(short8v*)(Wg_hi + base) = hi;
  *(short8v*)(Wg_lo + base) = lo;
}

// -------- kernel 3: ll[b][u][t] = hs[b,t,:] . W[:,lab(u)] + bias -----------
__global__ __launch_bounds__(256) void k_labg(const short* __restrict__ hsb,
                                              const short* __restrict__ Wg_hi,
                                              const short* __restrict__ Wg_lo,
                                              const int* __restrict__ ys,
                                              const float* __restrict__ bias,
                                              float* __restrict__ ll) {
  __shared__ short As[128 * 64];
  __shared__ short Bh[128 * 64];
  __shared__ short Bl[128 * 64];

  int mt = blockIdx.x, b = blockIdx.y;
  int t0 = mt * 128;
  int tid = threadIdx.x;
  int lane = tid & 63, wave = tid >> 6;
  int wm = wave >> 1, wn = wave & 1;
  int lrow = lane & 15, lkhi = lane >> 4;

  const short* gaBase = hsb + (size_t)(b * NT + t0 + wave * 32 + (lane >> 3)) * ND + (lane & 7) * 8;

  float4v acc[4][4];
#pragma unroll
  for (int m = 0; m < 4; ++m)
#pragma unroll
    for (int n = 0; n < 4; ++n)
#pragma unroll
      for (int j = 0; j < 4; ++j) acc[m][n][j] = 0.f;

  for (int s = 0; s < 8; ++s) {
    int k0 = s * 64;
#pragma unroll
    for (int i = 0; i < 4; ++i) {
      g2lds16(gaBase + (size_t)(i * 8) * ND + k0, &As[(wave * 32 + i * 8) * 64]);
      int brow = wave * 32 + (lane >> 3) + i * 8;
      int brc = (brow < NWG - 1) ? brow : (NWG - 1);
      g2lds16(Wg_hi + (size_t)(b * NWG + brc) * ND + (lane & 7) * 8 + k0,
              &Bh[(wave * 32 + i * 8) * 64]);
      g2lds16(Wg_lo + (size_t)(b * NWG + brc) * ND + (lane & 7) * 8 + k0,
              &Bl[(wave * 32 + i * 8) * 64]);
    }
    __syncthreads();
#pragma unroll
    for (int kk = 0; kk < 2; ++kk) {
      short8v av[4], bhv[4], blv2[4];
#pragma unroll
      for (int m = 0; m < 4; ++m) {
        int r = wm * 64 + m * 16 + lrow;
        int col = (kk * 32 + lkhi * 8) ^ ((r & 7) << 3);
        av[m] = *(const short8v*)&As[r * 64 + col];
      }
#pragma unroll
      for (int n = 0; n < 4; ++n) {
        int r = wn * 64 + n * 16 + lrow;
        int col = (kk * 32 + lkhi * 8) ^ ((r & 7) << 3);
        bhv[n] = *(const short8v*)&Bh[r * 64 + col];
        blv2[n] = *(const short8v*)&Bl[r * 64 + col];
      }
#pragma unroll
      for (int m = 0; m < 4; ++m)
#pragma unroll
        for (int n = 0; n < 4; ++n) {
          acc[m][n] = __builtin_amdgcn_mfma_f32_16x16x32_bf16(av[m], bhv[n], acc[m][n], 0, 0, 0);
          acc[m][n] = __builtin_amdgcn_mfma_f32_16x16x32_bf16(av[m], blv2[n], acc[m][n], 0, 0, 0);
        }
    }
    __syncthreads();
  }

  float bu[4]; bool uval[4];
#pragma unroll
  for (int n = 0; n < 4; ++n) {
    int u = wn * 64 + n * 16 + lrow;
    uval[n] = u < NU + 1;
    int lab = (u == 0) ? 0 : (uval[n] ? ys[b * NU + u - 1] : 0);
    bu[n] = uval[n] ? bias[lab] : 0.f;
  }
#pragma unroll
  for (int m = 0; m < 4; ++m)
#pragma unroll
    for (int j = 0; j < 4; ++j) {
      int trow = t0 + wm * 64 + m * 16 + lkhi * 4 + j;
      if (trow < NT) {
#pragma unroll
        for (int n = 0; n < 4; ++n) {
          int u = wn * 64 + n * 16 + lrow;
          if (uval[n])
            ll[((size_t)(b * NLL + u)) * NT + trow] = acc[m][n][j] + bu[n];
        }
      }
    }
}

// ---- kernel 4 (k_big): blocks 0..15 = FORWARD trellis (ll-domain, safe:
// no lsub sentinel); blocks 16..5015 = denom GEMM -> L chunk partials. ----
__global__ __launch_bounds__(256) void k_big(const short* __restrict__ hsb,
                                             const short* __restrict__ WT,
                                             const float* __restrict__ bias,
                                             const float* __restrict__ ll,
                                             const int* __restrict__ ys,
                                             float* __restrict__ L,
                                             float* __restrict__ aod) {
  __shared__ short As[128 * 64];
  __shared__ short Ws[128 * 64];
  __shared__ float mred[128][2];
  __shared__ float sred[128][2];

  int bid = blockIdx.x;
  int tid = threadIdx.x;

  if (bid < NB) {
    // ---------------- forward (alpha_ll, base-2) ----------------
    float* blkS = (float*)As;
    int b = bid;
    const float* llb = ll + (size_t)b * NLL * NT;
    for (int i = tid; i < NT; i += 256) blkS[i] = llb[i];
    __syncthreads();
    if (tid >= 64) return;
    int l = tid;
    const float* lrow = llb + (size_t)(1 + l) * NT;

    int lab = ys[b * NU + l];
    int labp = ys[b * NU + ((l >= 1) ? (l - 1) : 0)];
    bool skip = (l >= 1) && (lab != labp);
    float* aodb = aod + (size_t)b * NT * NU;

    float ae = (l == 0) ? blkS[0] * LOG2E : SENTL;
    float ao = (l == 0) ? lrow[0] * LOG2E : SENTL;
    aodb[l] = ao;

    float cl[16];
#pragma unroll
    for (int j = 0; j < 16; ++j) {
      int tt = 1 + j; if (tt > NT - 1) tt = NT - 1;
      cl[j] = lrow[tt];
    }
    for (int g = 0; g < 63; ++g) {
      float nl[16];
      if (g < 62) {
#pragma unroll
        for (int j = 0; j < 16; ++j) {
          int tt = 17 + g * 16 + j; if (tt > NT - 1) tt = NT - 1;
          nl[j] = lrow[tt];
        }
      } else {
#pragma unroll
        for (int j = 0; j < 16; ++j) nl[j] = 0.f;
      }
#pragma unroll
      for (int j = 0; j < 16; ++j) {
        int t = 1 + g * 16 + j;
        if (t < NT) {
          float pb = blkS[t] * LOG2E, pl = cl[j] * LOG2E;
          float po = dpp_shr1(ao); if (l == 0) po = SENTL;
          float aen = pb + lae2s(ae, po);
          float aon = pl + lae3s(ao, ae, skip ? po : SENTL);
          ae = aen; ao = aon;
          aodb[t * NU + l] = ao;
        }
      }
#pragma unroll
      for (int j = 0; j < 16; ++j) cl[j] = nl[j];
    }
    return;
  }

  // ---------------- denom GEMM (R9-verified structure) ----------------
  int lin = bid - NB;                         // 0..4999; 16%8==0 keeps XCD align
  int o = (lin & 7) * 625 + (lin >> 3);
  int mt, chunk;
  if (o < 4800) {
    int sb = o / 320, w = o % 320;
    mt = sb * 8 + (w & 7);
    chunk = w >> 3;
  } else {
    int w = o - 4800;
    mt = 120 + (w % 5);
    chunk = w / 5;
  }
  int t0 = mt * 128;
  int n0 = chunk * 128;
  int lane = tid & 63, wave = tid >> 6;
  int wm = wave >> 1, wn = wave & 1;
  int lrow = lane & 15, lkhi = lane >> 4;

  const short* gaBase = hsb + (size_t)(t0 + wave * 32 + (lane >> 3)) * ND + (lane & 7) * 8;
  const short* gwBase = WT + (size_t)(n0 + wave * 32 + (lane >> 3)) * ND + (lane & 7) * 8;

  float4v acc[4][4];
#pragma unroll
  for (int m = 0; m < 4; ++m)
#pragma unroll
    for (int n = 0; n < 4; ++n)
#pragma unroll
      for (int j = 0; j < 4; ++j) acc[m][n][j] = 0.f;

  for (int s = 0; s < 8; ++s) {
    int k0 = s * 64;
#pragma unroll
    for (int i = 0; i < 4; ++i) {
      g2lds16(gaBase + (size_t)(i * 8) * ND + k0, &As[(wave * 32 + i * 8) * 64]);
      g2lds16(gwBase + (size_t)(i * 8) * ND + k0, &Ws[(wave * 32 + i * 8) * 64]);
    }
    __syncthreads();
#pragma unroll
    for (int kk = 0; kk < 2; ++kk) {
      short8v av[4], wv[4];
#pragma unroll
      for (int m = 0; m < 4; ++m) {
        int r = wm * 64 + m * 16 + lrow;
        int col = (kk * 32 + lkhi * 8) ^ ((r & 7) << 3);
        av[m] = *(const short8v*)&As[r * 64 + col];
      }
#pragma unroll
      for (int n = 0; n < 4; ++n) {
        int r = wn * 64 + n * 16 + lrow;
        int col = (kk * 32 + lkhi * 8) ^ ((r & 7) << 3);
        wv[n] = *(const short8v*)&Ws[r * 64 + col];
      }
#pragma unroll
      for (int m = 0; m < 4; ++m)
#pragma unroll
        for (int n = 0; n < 4; ++n)
          acc[m][n] = __builtin_amdgcn_mfma_f32_16x16x32_bf16(av[m], wv[n], acc[m][n], 0, 0, 0);
    }
    __syncthreads();
  }

  float bcol[4]; bool cval[4];
#pragma unroll
  for (int n = 0; n < 4; ++n) {
    int c = n0 + wn * 64 + n * 16 + lrow;
    cval[n] = c < NV;
    bcol[n] = cval[n] ? bias[c] : 0.f;
  }
#pragma unroll
  for (int m = 0; m < 4; ++m)
#pragma unroll
    for (int j = 0; j < 4; ++j) {
      float mx = NEGINF;
#pragma unroll
      for (int n = 0; n < 4; ++n) {
        float v = cval[n] ? acc[m][n][j] + bcol[n] : NEGINF;
        mx = fmaxf(mx, v);
      }
#pragma unroll
      for (int d = 1; d < 16; d <<= 1) mx = fmaxf(mx, __shfl_xor(mx, d));
      float mxc = fmaxf(mx, -3.0e38f);
      float p = 0.f;
#pragma unroll
      for (int n = 0; n < 4; ++n) {
        float v = cval[n] ? acc[m][n][j] + bcol[n] : NEGINF;
        p += __expf(v - mxc);
      }
#pragma unroll
      for (int d = 1; d < 16; d <<= 1) p += __shfl_xor(p, d);
      if (lrow == 0) {
        int rloc = wm * 64 + m * 16 + lkhi * 4 + j;
        mred[rloc][wn] = mx;
        sred[rloc][wn] = p;
      }
    }
  __syncthreads();
  if (tid < 128) {
    int row = t0 + tid;
    float m0 = mred[tid][0], m1 = mred[tid][1];
    float m = fmaxf(m0, m1);
    float ss = 0.f;
    if (m != NEGINF)
      ss = ((m0 == NEGINF) ? 0.f : sred[tid][0] * __expf(m0 - m))
         + ((m1 == NEGINF) ? 0.f : sred[tid][1] * __expf(m1 - m));
    float Lv = (m == NEGINF || ss <= 0.f) ? NEGINF : m + __logf(ss);
    L[(size_t)chunk * NM + row] = Lv;
  }
}

// ---- kernel 5 (k_bwd): backward trellis in NORMALIZED domain (R9-proven).
// Stages denL from L partials itself (replaces k_dred).
__global__ __launch_bounds__(256) void k_bwd(const float* __restrict__ ll,
                                             const float* __restrict__ L,
                                             const int* __restrict__ ys,
                                             float* __restrict__ bp) {
  __shared__ float denS[NT];
  __shared__ float blkS[NT];
  int b = blockIdx.x;
  int tid = threadIdx.x;
  const float* llb = ll + (size_t)b * NLL * NT;
  for (int t = tid; t < NT; t += 256) {
    int row = b * NT + t;
    float m40 = NEGINF;
#pragma unroll 4
    for (int c = 0; c < NCH; ++c) m40 = fmaxf(m40, L[(size_t)c * NM + row]);
    float s = 0.f;
#pragma unroll 4
    for (int c = 0; c < NCH; ++c) {
      float Lc = L[(size_t)c * NM + row];
      if (Lc > -1.0e29f) s += __expf(Lc - m40);
    }
    denS[t] = m40 + __logf(s);
    blkS[t] = llb[t];
  }
  __syncthreads();
  if (tid >= 64) return;
  int l = tid;
  const float* lrow = llb + (size_t)(1 + l) * NT;

  int lab = ys[b * NU + l];
  int labn = ys[b * NU + ((l < NU - 1) ? (l + 1) : l)];
  bool skipn = (l < NU - 1) && (labn != lab);
  float* bpb = bp + (size_t)b * NT * NU;

  float bo = (l == NU - 1) ? 0.0f : SENTL;
  float be = SENTL;
  float b128 = 0.0f;
  bpb[(NT - 1) * NU + l] = bo;

  float blv[16];
#pragma unroll
  for (int j = 0; j < 16; ++j) {
    int tt = NT - 2 - j; if (tt < 0) tt = 0;
    blv[j] = lrow[tt + 1];
  }
  for (int g = 0; g < 63; ++g) {
    float nl2[16];
    if (g < 62) {
#pragma unroll
      for (int j = 0; j < 16; ++j) {
        int tt = NT - 2 - 16 * (g + 1) - j; if (tt < 0) tt = 0;
        nl2[j] = lrow[tt + 1];
      }
    } else {
#pragma unroll
      for (int j = 0; j < 16; ++j) nl2[j] = 0.f;
    }
#pragma unroll
    for (int j = 0; j < 16; ++j) {
      int t = NT - 2 - 16 * g - j;
      if (t >= 0) {
        float d2 = denS[t + 1];
        float pbv = (blkS[t + 1] - d2) * LOG2E, plv = (blv[j] - d2) * LOG2E;
        float me = pbv + be;
        float mo = plv + bo;
        float m128 = pbv + b128;
        float ne = dpp_shl1(me); if (l == NU - 1) ne = m128;
        float no = dpp_shl1(mo); if (l == NU - 1) no = SENTL;
        float ben = lae2s(me, mo);
        float bon = lae3s(mo, ne, skipn ? no : SENTL);
        bpb[t * NU + l] = lsub2(bon, mo);
        be = ben; bo = bon; b128 = m128;
      }
    }
#pragma unroll
    for (int j = 0; j < 16; ++j) blv[j] = nl2[j];
  }
}

// ---- kernel 6: loss. alpha re-normalized per-t (Dpre prefix); bp already
// normalized -> x matches reference loss_state, incl. sentinel stats. ----
__global__ __launch_bounds__(512) void k_loss(const float* __restrict__ aod,
                                              const float* __restrict__ bp,
                                              const float* __restrict__ L,
                                              const int* __restrict__ hlens,
                                              float* __restrict__ out) {
  __shared__ float denL[NT];
  __shared__ float Dpre[NT];
  __shared__ float choff[64];
  __shared__ float ms[8][64], ss[8][64];
  int b = blockIdx.x, tid = threadIdx.x;
  for (int t = tid; t < NT; t += 512) {
    int row = b * NT + t;
    float m40 = NEGINF;
#pragma unroll 4
    for (int c = 0; c < NCH; ++c) m40 = fmaxf(m40, L[(size_t)c * NM + row]);
    float s = 0.f;
#pragma unroll 4
    for (int c = 0; c < NCH; ++c) {
      float Lc = L[(size_t)c * NM + row];
      if (Lc > -1.0e29f) s += __expf(Lc - m40);
    }
    denL[t] = m40 + __logf(s);
  }
  __syncthreads();
  if (tid < 64) {
    float s = 0.f;
#pragma unroll
    for (int i = 0; i < 16; ++i) { int t = tid * 16 + i; if (t < NT) s += denL[t]; }
    float v = s;
#pragma unroll
    for (int d = 1; d < 64; d <<= 1) { float u = __shfl_up(v, d); if (tid >= d) v += u; }
    choff[tid] = v - s;
  }
  __syncthreads();
  for (int t = tid; t < NT; t += 512) {
    float s = choff[t >> 4];
    int base = t & ~15;
    for (int i = base; i <= t; ++i) s += denL[i];
    Dpre[t] = s;   // inclusive prefix D(t)
  }
  __syncthreads();
  int w = tid >> 6, l = tid & 63;
  const float* ab = aod + (size_t)b * NT * NU;
  const float* pbp = bp + (size_t)b * NT * NU;
  float m = NEGINF, s = 0.f;
  int t0 = w * 125, t1 = t0 + 125;
  for (int t = t0; t < t1; ++t) {
    float av = ab[t * NU + l];          // alpha_ll (base-2)
    float pv = pbp[t * NU + l];         // bp normalized (base-2)
    float x = av - Dpre[t] * LOG2E + pv;
    if (__builtin_isnan(x) || x < -1.0e29f) continue;
    if (x > m) { s = s * fexp2(m - x) + 1.0f; m = x; }
    else       { s += fexp2(x - m); }
  }
  ms[w][l] = m; ss[w][l] = s;
  __syncthreads();
  if (w == 0) {
    float mm = NEGINF;
#pragma unroll
    for (int i = 0; i < 8; ++i) mm = fmaxf(mm, ms[i][l]);
    float lu;
    if (mm == NEGINF) lu = NEGINF;
    else {
      float st = 0.f;
#pragma unroll
      for (int i = 0; i < 8; ++i)
        st += (ms[i][l] == NEGINF) ? 0.f : ss[i][l] * fexp2(ms[i][l] - mm);
      lu = (mm + flog2(st)) * LN2F;
    }
    bool msk = __builtin_isinf(lu);
    float sv = msk ? 0.f : lu;
    float cv = msk ? 0.f : 1.f;
#pragma unroll
    for (int d = 1; d < 64; d <<= 1) { sv += __shfl_xor(sv, d); cv += __shfl_xor(cv, d); }
    if (l == 0) {
      float lf = sv / cv;
      if (hlens[b] < NU) lf = 0.f;
      atomicAdd(out, -lf * (1.0f / NB));
    }
  }
}

// ---------------------------------------------------------------------------
extern "C" void kernel_launch(void* const* d_in, const int* in_sizes, int n_in,
                              void* d_out, int out_size, void* d_ws, size_t ws_size,
                              hipStream_t stream) {
  const float* hs    = (const float*)d_in[0];
  const int*   hlens = (const int*)d_in[1];
  const int*   ys    = (const int*)d_in[2];
  const float* W     = (const float*)d_in[4];
  const float* bias  = (const float*)d_in[5];
  float* out = (float*)d_out;

  char* ws = (char*)d_ws;
  short* hsb   = (short*)(ws + 0);           // 16,384,000 B  live thru k_big
  short* WT    = (short*)(ws + 16384000);    //  5,242,880 B  live thru k_big
  short* WTlo  = (short*)(ws + 21626880);    //  5,242,880 B  dead after k_gather2
  float* ll    = (float*)(ws + 21626880);    //  4,224,000 B  aliases WTlo (k_labg writes)
  float* L     = (float*)(ws + 25850880);    //  2,560,000 B  live thru k_loss
  short* Wg_hi = (short*)(ws + 28410880);    //  1,179,648 B  dead after k_labg
  short* Wg_lo = (short*)(ws + 29590528);    //  1,179,648 B
  float* aod   = (float*)(ws + 28410880);    //  4,096,000 B  aliases Wg (k_big writes)
  float* bpb   = (float*)(ws + 32506880);    //  4,096,000 B  (end 36,602,880)

  k_cvt<<<4640, 256, 0, stream>>>(hs, W, hsb, WT, WTlo, out);
  k_gather2<<<dim3(NWG, 16), 64, 0, stream>>>(WT, WTlo, ys, Wg_hi, Wg_lo);
  k_labg<<<dim3(8, 16), 256, 0, stream>>>(hsb, Wg_hi, Wg_lo, ys, bias, ll);
  k_big<<<5016, 256, 0, stream>>>(hsb, WT, bias, ll, ys, L, aod);
  k_bwd<<<NB, 256, 0, stream>>>(ll, L, ys, bpb);
  k_loss<<<16, 512, 0, stream>>>(aod, bpb, L, hlens, out);
}

// Round 14
// 372.456 us; speedup vs baseline: 1.1519x; 1.1519x over previous
//
#include <hip/hip_runtime.h>

// Problem constants (SpeakerAwareCTC): B=16, T=1000, D=512, V=5000, U=64, S=2U+1=129
#define NB 16
#define NT 1000
#define ND 512
#define NV 5000
#define NVP 5120          // WT padded rows (zeros beyond 5000)
#define NU 64
#define NLL 66            // ll row stride (u-major rows, 65 used)
#define NWG 72            // Wg padded u-rows
#define NM (NB * NT)      // 16000 flattened rows
#define NCH 40            // N-chunks of 128 cols

typedef short short8v __attribute__((ext_vector_type(8)));
typedef float float4v __attribute__((ext_vector_type(4)));

#define NEGINF (-__builtin_inff())
#define SENTL  (-1.0e30f)   // finite "-inf"
#define LOG2E 1.4426950408889634f
#define LN2F  0.6931471805599453f
// reference sentinel: -2001 + logf(expf(1)-1) = -2000.4586751f (natural), base-2:
#define SENT2 (-2000.4586751f * LOG2E)

__device__ __forceinline__ float fexp2(float x) { return __builtin_amdgcn_exp2f(x); }
__device__ __forceinline__ float flog2(float x) { return __builtin_amdgcn_logf(x); }

__device__ __forceinline__ float dpp_shr1(float x) {  // lane i <- lane i-1
  int xi = __builtin_bit_cast(int, x);
  int r = __builtin_amdgcn_update_dpp(xi, xi, 0x138, 0xf, 0xf, false);
  return __builtin_bit_cast(float, r);
}
__device__ __forceinline__ float dpp_shl1(float x) {  // lane i <- lane i+1
  int xi = __builtin_bit_cast(int, x);
  int r = __builtin_amdgcn_update_dpp(xi, xi, 0x130, 0xf, 0xf, false);
  return __builtin_bit_cast(float, r);
}

__device__ __forceinline__ short f2bf(float x) {
  unsigned int u = __builtin_bit_cast(unsigned int, x);
  unsigned int r = (u + 0x7fffu + ((u >> 16) & 1u)) >> 16;
  return (short)(unsigned short)r;
}
__device__ __forceinline__ float bf2f(short h) {
  unsigned int u = ((unsigned int)(unsigned short)h) << 16;
  return __builtin_bit_cast(float, u);
}

__device__ __forceinline__ void g2lds16(const short* g, short* l) {
  __builtin_amdgcn_global_load_lds(
      (const __attribute__((address_space(1))) void*)g,
      (__attribute__((address_space(3))) void*)l, 16, 0, 0);
}

__device__ __forceinline__ float lae2s(float a, float b) {
  float m = fmaxf(a, b);
  return m + flog2(fexp2(a - m) + fexp2(b - m));
}
__device__ __forceinline__ float lae3s(float a, float b, float c) {
  float m = fmaxf(fmaxf(a, b), c);
  return m + flog2(fexp2(a - m) + fexp2(b - m) + fexp2(c - m));
}
// faithful log_substraction_exp (normalized domain, finite sentinels)
__device__ __forceinline__ float lsub2(float a, float b) {
  if (b < -1.0e29f) return (a < -1.0e29f) ? SENTL : a;
  float tmp = b + flog2(fexp2(a - b) - 1.0f);
  if (__builtin_isinf(tmp)) tmp = SENT2;
  return tmp;   // NaN (a<b rounding) passes through -> masked in k_loss
}

// ------ kernel 1: fused converts: hs->bf16 swizzled | W->WT/WTlo ----------
__global__ __launch_bounds__(256) void k_cvt(const float* __restrict__ hs,
                                             const float* __restrict__ W,
                                             short* __restrict__ hsb,
                                             short* __restrict__ WT,
                                             short* __restrict__ WTlo,
                                             float* __restrict__ outv) {
  __shared__ short tileH[64 * 72];
  __shared__ short tileL[64 * 72];
  if (blockIdx.x < 4000) {
    if (blockIdx.x == 0 && threadIdx.x == 0) outv[0] = 0.0f;
    size_t i = (size_t)blockIdx.x * 256 + threadIdx.x;
    const float4* p = (const float4*)hs + i * 2;
    float4 v0 = p[0], v1 = p[1];
    short8v r;
    r[0] = f2bf(v0.x); r[1] = f2bf(v0.y); r[2] = f2bf(v0.z); r[3] = f2bf(v0.w);
    r[4] = f2bf(v1.x); r[5] = f2bf(v1.y); r[6] = f2bf(v1.z); r[7] = f2bf(v1.w);
    int row = (int)(i >> 6);
    int g = (int)(i & 63);
    int gs = (g & ~7) | ((g & 7) ^ (row & 7));
    *(short8v*)(hsb + (size_t)row * ND + gs * 8) = r;
    return;
  }
  int bx = blockIdx.x - 4000;
  int n0 = (bx % 80) * 64, k0 = (bx / 80) * 64;
  int tid = threadIdx.x;
  int kr = tid >> 2, part = tid & 3;
  const float* src = W + (size_t)(k0 + kr) * NV + n0 + part * 16;
#pragma unroll
  for (int jj = 0; jj < 4; ++jj) {
    int c = n0 + part * 16 + jj * 4;
    float4 v;
    if (c + 3 < NV) {
      v = *(const float4*)(src + jj * 4);
    } else {
      v.x = (c + 0 < NV) ? src[jj * 4 + 0] : 0.f;
      v.y = (c + 1 < NV) ? src[jj * 4 + 1] : 0.f;
      v.z = (c + 2 < NV) ? src[jj * 4 + 2] : 0.f;
      v.w = (c + 3 < NV) ? src[jj * 4 + 3] : 0.f;
    }
    int base = kr * 72 + part * 16 + jj * 4;
    float vv[4] = {v.x, v.y, v.z, v.w};
#pragma unroll
    for (int q = 0; q < 4; ++q) {
      short h = f2bf(vv[q]);
      tileH[base + q] = h;
      tileL[base + q] = f2bf(vv[q] - bf2f(h));
    }
  }
  __syncthreads();
  int n = tid & 63, kq = tid >> 6;
  int nn = n0 + n;
  if (nn < NVP) {
#pragma unroll
    for (int half = 0; half < 2; ++half) {
      short8v vh, vl;
#pragma unroll
      for (int jj = 0; jj < 8; ++jj) {
        vh[jj] = tileH[(kq * 16 + half * 8 + jj) * 72 + n];
        vl[jj] = tileL[(kq * 16 + half * 8 + jj) * 72 + n];
      }
      int g = (k0 >> 3) + kq * 2 + half;
      int gs = (g & ~7) | ((g & 7) ^ (nn & 7));
      *(short8v*)(WT + (size_t)nn * ND + gs * 8) = vh;
      *(short8v*)(WTlo + (size_t)nn * ND + gs * 8) = vl;
    }
  }
}

// -------- kernel 2: gather Wg_hi/lo[b][u][k] from WT/WTlo rows -------------
__global__ __launch_bounds__(64) void k_gather2(const short* __restrict__ WT,
                                                const short* __restrict__ WTlo,
                                                const int* __restrict__ ys,
                                                short* __restrict__ Wg_hi,
                                                short* __restrict__ Wg_lo) {
  int u = blockIdx.x, b = blockIdx.y, t = threadIdx.x;
  short8v hi = {0,0,0,0,0,0,0,0}, lo = {0,0,0,0,0,0,0,0};
  if (u < NU + 1) {
    int lab = (u == 0) ? 0 : ys[b * NU + u - 1];
    int ps = (t & ~7) | ((t & 7) ^ (lab & 7));
    hi = *(const short8v*)(WT + (size_t)lab * ND + ps * 8);
    lo = *(const short8v*)(WTlo + (size_t)lab * ND + ps * 8);
  }
  int q = (t & ~7) | ((t & 7) ^ (u & 7));
  size_t base = ((size_t)(b * NWG + u)) * ND + q * 8;
  *(short8v*)(Wg_hi + base) = hi;
  *(short8v*)(Wg_lo + base) = lo;
}

// -------- kernel 3: ll[b][u][t] = hs[b,t,:] . W[:,lab(u)] + bias -----------
__global__ __launch_bounds__(256) void k_labg(const short* __restrict__ hsb,
                                              const short* __restrict__ Wg_hi,
                                              const short* __restrict__ Wg_lo,
                                              const int* __restrict__ ys,
                                              const float* __restrict__ bias,
                                              float* __restrict__ ll) {
  __shared__ short As[128 * 64];
  __shared__ short Bh[128 * 64];
  __shared__ short Bl[128 * 64];

  int mt = blockIdx.x, b = blockIdx.y;
  int t0 = mt * 128;
  int tid = threadIdx.x;
  int lane = tid & 63, wave = tid >> 6;
  int wm = wave >> 1, wn = wave & 1;
  int lrow = lane & 15, lkhi = lane >> 4;

  const short* gaBase = hsb + (size_t)(b * NT + t0 + wave * 32 + (lane >> 3)) * ND + (lane & 7) * 8;

  float4v acc[4][4];
#pragma unroll
  for (int m = 0; m < 4; ++m)
#pragma unroll
    for (int n = 0; n < 4; ++n)
#pragma unroll
      for (int j = 0; j < 4; ++j) acc[m][n][j] = 0.f;

  for (int s = 0; s < 8; ++s) {
    int k0 = s * 64;
#pragma unroll
    for (int i = 0; i < 4; ++i) {
      g2lds16(gaBase + (size_t)(i * 8) * ND + k0, &As[(wave * 32 + i * 8) * 64]);
      int brow = wave * 32 + (lane >> 3) + i * 8;
      int brc = (brow < NWG - 1) ? brow : (NWG - 1);
      g2lds16(Wg_hi + (size_t)(b * NWG + brc) * ND + (lane & 7) * 8 + k0,
              &Bh[(wave * 32 + i * 8) * 64]);
      g2lds16(Wg_lo + (size_t)(b * NWG + brc) * ND + (lane & 7) * 8 + k0,
              &Bl[(wave * 32 + i * 8) * 64]);
    }
    __syncthreads();
#pragma unroll
    for (int kk = 0; kk < 2; ++kk) {
      short8v av[4], bhv[4], blv2[4];
#pragma unroll
      for (int m = 0; m < 4; ++m) {
        int r = wm * 64 + m * 16 + lrow;
        int col = (kk * 32 + lkhi * 8) ^ ((r & 7) << 3);
        av[m] = *(const short8v*)&As[r * 64 + col];
      }
#pragma unroll
      for (int n = 0; n < 4; ++n) {
        int r = wn * 64 + n * 16 + lrow;
        int col = (kk * 32 + lkhi * 8) ^ ((r & 7) << 3);
        bhv[n] = *(const short8v*)&Bh[r * 64 + col];
        blv2[n] = *(const short8v*)&Bl[r * 64 + col];
      }
#pragma unroll
      for (int m = 0; m < 4; ++m)
#pragma unroll
        for (int n = 0; n < 4; ++n) {
          acc[m][n] = __builtin_amdgcn_mfma_f32_16x16x32_bf16(av[m], bhv[n], acc[m][n], 0, 0, 0);
          acc[m][n] = __builtin_amdgcn_mfma_f32_16x16x32_bf16(av[m], blv2[n], acc[m][n], 0, 0, 0);
        }
    }
    __syncthreads();
  }

  float bu[4]; bool uval[4];
#pragma unroll
  for (int n = 0; n < 4; ++n) {
    int u = wn * 64 + n * 16 + lrow;
    uval[n] = u < NU + 1;
    int lab = (u == 0) ? 0 : (uval[n] ? ys[b * NU + u - 1] : 0);
    bu[n] = uval[n] ? bias[lab] : 0.f;
  }
#pragma unroll
  for (int m = 0; m < 4; ++m)
#pragma unroll
    for (int j = 0; j < 4; ++j) {
      int trow = t0 + wm * 64 + m * 16 + lkhi * 4 + j;
      if (trow < NT) {
#pragma unroll
        for (int n = 0; n < 4; ++n) {
          int u = wn * 64 + n * 16 + lrow;
          if (uval[n])
            ll[((size_t)(b * NLL + u)) * NT + trow] = acc[m][n][j] + bu[n];
        }
      }
    }
}

// ---- kernel 4 (k_big): blocks 0..15 = FORWARD trellis (ll-domain);
// blocks 16..5015 = denom GEMM -> L chunk partials. Chain is register-only. --
__global__ __launch_bounds__(256) void k_big(const short* __restrict__ hsb,
                                             const short* __restrict__ WT,
                                             const float* __restrict__ bias,
                                             const float* __restrict__ ll,
                                             const int* __restrict__ ys,
                                             float* __restrict__ L,
                                             float* __restrict__ aod) {
  __shared__ short As[128 * 64];
  __shared__ short Ws[128 * 64];
  __shared__ float mred[128][2];
  __shared__ float sred[128][2];

  int bid = blockIdx.x;
  int tid = threadIdx.x;

  if (bid < NB) {
    // ---------------- forward (alpha_ll, base-2) ----------------
    float* pbS = (float*)As;   // pbS[t] = ll_blank[t]*LOG2E  (4 KB)
    int b = bid;
    const float* llb = ll + (size_t)b * NLL * NT;
    for (int i = tid; i < NT; i += 256) pbS[i] = llb[i] * LOG2E;
    __syncthreads();
    if (tid >= 64) return;
    int l = tid;
    const float* lrow = llb + (size_t)(1 + l) * NT;

    int lab = ys[b * NU + l];
    int labp = ys[b * NU + ((l >= 1) ? (l - 1) : 0)];
    bool skip = (l >= 1) && (lab != labp);
    float* aodb = aod + (size_t)b * NT * NU;

    float ae = (l == 0) ? pbS[0] : SENTL;
    float ao = (l == 0) ? lrow[0] * LOG2E : SENTL;
    aodb[l] = ao;

    float cl[16], pbr[16];
#pragma unroll
    for (int j = 0; j < 16; ++j) {
      int tt = 1 + j; if (tt > NT - 1) tt = NT - 1;
      cl[j] = lrow[tt];
      pbr[j] = pbS[tt];
    }
    for (int g = 0; g < 63; ++g) {
      float nl[16], pb2[16];
      if (g < 62) {
#pragma unroll
        for (int j = 0; j < 16; ++j) {
          int tt = 17 + g * 16 + j; if (tt > NT - 1) tt = NT - 1;
          nl[j] = lrow[tt];
          pb2[j] = pbS[tt];
        }
      } else {
#pragma unroll
        for (int j = 0; j < 16; ++j) { nl[j] = 0.f; pb2[j] = 0.f; }
      }
#pragma unroll
      for (int j = 0; j < 16; ++j) {
        int t = 1 + g * 16 + j;
        if (t < NT) {
          float pb = pbr[j];            // register, off-chain
          float pl = cl[j] * LOG2E;     // register, off-chain
          float po = dpp_shr1(ao); if (l == 0) po = SENTL;
          float aen = pb + lae2s(ae, po);
          float aon = pl + lae3s(ao, ae, skip ? po : SENTL);
          ae = aen; ao = aon;
          aodb[t * NU + l] = ao;
        }
      }
#pragma unroll
      for (int j = 0; j < 16; ++j) { cl[j] = nl[j]; pbr[j] = pb2[j]; }
    }
    return;
  }

  // ---------------- denom GEMM (R9-verified structure) ----------------
  int lin = bid - NB;
  int o = (lin & 7) * 625 + (lin >> 3);
  int mt, chunk;
  if (o < 4800) {
    int sb = o / 320, w = o % 320;
    mt = sb * 8 + (w & 7);
    chunk = w >> 3;
  } else {
    int w = o - 4800;
    mt = 120 + (w % 5);
    chunk = w / 5;
  }
  int t0 = mt * 128;
  int n0 = chunk * 128;
  int lane = tid & 63, wave = tid >> 6;
  int wm = wave >> 1, wn = wave & 1;
  int lrow = lane & 15, lkhi = lane >> 4;

  const short* gaBase = hsb + (size_t)(t0 + wave * 32 + (lane >> 3)) * ND + (lane & 7) * 8;
  const short* gwBase = WT + (size_t)(n0 + wave * 32 + (lane >> 3)) * ND + (lane & 7) * 8;

  float4v acc[4][4];
#pragma unroll
  for (int m = 0; m < 4; ++m)
#pragma unroll
    for (int n = 0; n < 4; ++n)
#pragma unroll
      for (int j = 0; j < 4; ++j) acc[m][n][j] = 0.f;

  for (int s = 0; s < 8; ++s) {
    int k0 = s * 64;
#pragma unroll
    for (int i = 0; i < 4; ++i) {
      g2lds16(gaBase + (size_t)(i * 8) * ND + k0, &As[(wave * 32 + i * 8) * 64]);
      g2lds16(gwBase + (size_t)(i * 8) * ND + k0, &Ws[(wave * 32 + i * 8) * 64]);
    }
    __syncthreads();
#pragma unroll
    for (int kk = 0; kk < 2; ++kk) {
      short8v av[4], wv[4];
#pragma unroll
      for (int m = 0; m < 4; ++m) {
        int r = wm * 64 + m * 16 + lrow;
        int col = (kk * 32 + lkhi * 8) ^ ((r & 7) << 3);
        av[m] = *(const short8v*)&As[r * 64 + col];
      }
#pragma unroll
      for (int n = 0; n < 4; ++n) {
        int r = wn * 64 + n * 16 + lrow;
        int col = (kk * 32 + lkhi * 8) ^ ((r & 7) << 3);
        wv[n] = *(const short8v*)&Ws[r * 64 + col];
      }
#pragma unroll
      for (int m = 0; m < 4; ++m)
#pragma unroll
        for (int n = 0; n < 4; ++n)
          acc[m][n] = __builtin_amdgcn_mfma_f32_16x16x32_bf16(av[m], wv[n], acc[m][n], 0, 0, 0);
    }
    __syncthreads();
  }

  float bcol[4]; bool cval[4];
#pragma unroll
  for (int n = 0; n < 4; ++n) {
    int c = n0 + wn * 64 + n * 16 + lrow;
    cval[n] = c < NV;
    bcol[n] = cval[n] ? bias[c] : 0.f;
  }
#pragma unroll
  for (int m = 0; m < 4; ++m)
#pragma unroll
    for (int j = 0; j < 4; ++j) {
      float mx = NEGINF;
#pragma unroll
      for (int n = 0; n < 4; ++n) {
        float v = cval[n] ? acc[m][n][j] + bcol[n] : NEGINF;
        mx = fmaxf(mx, v);
      }
#pragma unroll
      for (int d = 1; d < 16; d <<= 1) mx = fmaxf(mx, __shfl_xor(mx, d));
      float mxc = fmaxf(mx, -3.0e38f);
      float p = 0.f;
#pragma unroll
      for (int n = 0; n < 4; ++n) {
        float v = cval[n] ? acc[m][n][j] + bcol[n] : NEGINF;
        p += __expf(v - mxc);
      }
#pragma unroll
      for (int d = 1; d < 16; d <<= 1) p += __shfl_xor(p, d);
      if (lrow == 0) {
        int rloc = wm * 64 + m * 16 + lkhi * 4 + j;
        mred[rloc][wn] = mx;
        sred[rloc][wn] = p;
      }
    }
  __syncthreads();
  if (tid < 128) {
    int row = t0 + tid;
    float m0 = mred[tid][0], m1 = mred[tid][1];
    float m = fmaxf(m0, m1);
    float ss = 0.f;
    if (m != NEGINF)
      ss = ((m0 == NEGINF) ? 0.f : sred[tid][0] * __expf(m0 - m))
         + ((m1 == NEGINF) ? 0.f : sred[tid][1] * __expf(m1 - m));
    float Lv = (m == NEGINF || ss <= 0.f) ? NEGINF : m + __logf(ss);
    L[(size_t)chunk * NM + row] = Lv;
  }
}

// ---- kernel 5 (k_dred): combine 40 chunk partials -> dnm[row], full unroll -
__global__ __launch_bounds__(256) void k_dred(const float* __restrict__ L,
                                              float* __restrict__ dnm) {
  int row = blockIdx.x * 256 + threadIdx.x;
  if (row >= NM) return;
  float m40 = NEGINF;
#pragma unroll
  for (int c = 0; c < NCH; ++c) m40 = fmaxf(m40, L[(size_t)c * NM + row]);
  float s = 0.f;
#pragma unroll
  for (int c = 0; c < NCH; ++c) {
    float Lc = L[(size_t)c * NM + row];
    if (Lc > -1.0e29f) s += __expf(Lc - m40);
  }
  dnm[row] = m40 + __logf(s);
}

// ---- kernel 6 (k_bwd): backward trellis, NORMALIZED domain, register chain -
__global__ __launch_bounds__(256) void k_bwd(const float* __restrict__ ll,
                                             const float* __restrict__ dnm,
                                             const int* __restrict__ ys,
                                             float* __restrict__ bp) {
  __shared__ float dnS[NT];   // raw den
  __shared__ float pbS[NT];   // (blank - den)*LOG2E
  int b = blockIdx.x;
  int tid = threadIdx.x;
  const float* llb = ll + (size_t)b * NLL * NT;
  const float* dnb = dnm + b * NT;
  for (int t = tid; t < NT; t += 256) {
    float d = dnb[t];
    float blk = llb[t];
    dnS[t] = d;
    pbS[t] = (blk - d) * LOG2E;
  }
  __syncthreads();
  if (tid >= 64) return;
  int l = tid;
  const float* lrow = llb + (size_t)(1 + l) * NT;

  int lab = ys[b * NU + l];
  int labn = ys[b * NU + ((l < NU - 1) ? (l + 1) : l)];
  bool skipn = (l < NU - 1) && (labn != lab);
  float* bpb = bp + (size_t)b * NT * NU;

  float bo = (l == NU - 1) ? 0.0f : SENTL;
  float be = SENTL;
  float b128 = 0.0f;
  bpb[(NT - 1) * NU + l] = bo;

  float cl[16], pbr[16], dnr[16];
#pragma unroll
  for (int j = 0; j < 16; ++j) {
    int tt = NT - 2 - j; if (tt < 0) tt = 0;
    cl[j] = lrow[tt + 1];
    pbr[j] = pbS[tt + 1];
    dnr[j] = dnS[tt + 1];
  }
  for (int g = 0; g < 63; ++g) {
    float nl2[16], pb2[16], dn2[16];
    if (g < 62) {
#pragma unroll
      for (int j = 0; j < 16; ++j) {
        int tt = NT - 2 - 16 * (g + 1) - j; if (tt < 0) tt = 0;
        nl2[j] = lrow[tt + 1];
        pb2[j] = pbS[tt + 1];
        dn2[j] = dnS[tt + 1];
      }
    } else {
#pragma unroll
      for (int j = 0; j < 16; ++j) { nl2[j] = 0.f; pb2[j] = 0.f; dn2[j] = 0.f; }
    }
#pragma unroll
    for (int j = 0; j < 16; ++j) {
      int t = NT - 2 - 16 * g - j;
      if (t >= 0) {
        float pbv = pbr[j];                       // register, off-chain
        float plv = (cl[j] - dnr[j]) * LOG2E;     // register, off-chain
        float me = pbv + be;
        float mo = plv + bo;
        float m128 = pbv + b128;
        float ne = dpp_shl1(me); if (l == NU - 1) ne = m128;
        float no = dpp_shl1(mo); if (l == NU - 1) no = SENTL;
        float ben = lae2s(me, mo);
        float bon = lae3s(mo, ne, skipn ? no : SENTL);
        bpb[t * NU + l] = lsub2(bon, mo);
        be = ben; bo = bon; b128 = m128;
      }
    }
#pragma unroll
    for (int j = 0; j < 16; ++j) { cl[j] = nl2[j]; pbr[j] = pb2[j]; dnr[j] = dn2[j]; }
  }
}

// ---- kernel 7: loss. alpha re-normalized per-t (Dpre prefix from dnm). ----
__global__ __launch_bounds__(512) void k_loss(const float* __restrict__ aod,
                                              const float* __restrict__ bp,
                                              const float* __restrict__ dnm,
                                              const int* __restrict__ hlens,
                                              float* __restrict__ out) {
  __shared__ float denL[NT];
  __shared__ float Dpre[NT];
  __shared__ float choff[64];
  __shared__ float ms[8][64], ss[8][64];
  int b = blockIdx.x, tid = threadIdx.x;
  for (int t = tid; t < NT; t += 512) denL[t] = dnm[b * NT + t];
  __syncthreads();
  if (tid < 64) {
    float s = 0.f;
#pragma unroll
    for (int i = 0; i < 16; ++i) { int t = tid * 16 + i; if (t < NT) s += denL[t]; }
    float v = s;
#pragma unroll
    for (int d = 1; d < 64; d <<= 1) { float u = __shfl_up(v, d); if (tid >= d) v += u; }
    choff[tid] = v - s;
  }
  __syncthreads();
  for (int t = tid; t < NT; t += 512) {
    float s = choff[t >> 4];
    int base = t & ~15;
    for (int i = base; i <= t; ++i) s += denL[i];
    Dpre[t] = s;   // inclusive prefix D(t)
  }
  __syncthreads();
  int w = tid >> 6, l = tid & 63;
  const float* ab = aod + (size_t)b * NT * NU;
  const float* pbp = bp + (size_t)b * NT * NU;
  float m = NEGINF, s = 0.f;
  int t0 = w * 125, t1 = t0 + 125;
  for (int t = t0; t < t1; ++t) {
    float av = ab[t * NU + l];          // alpha_ll (base-2)
    float pv = pbp[t * NU + l];         // bp normalized (base-2)
    float x = av - Dpre[t] * LOG2E + pv;
    if (__builtin_isnan(x) || x < -1.0e29f) continue;
    if (x > m) { s = s * fexp2(m - x) + 1.0f; m = x; }
    else       { s += fexp2(x - m); }
  }
  ms[w][l] = m; ss[w][l] = s;
  __syncthreads();
  if (w == 0) {
    float mm = NEGINF;
#pragma unroll
    for (int i = 0; i < 8; ++i) mm = fmaxf(mm, ms[i][l]);
    float lu;
    if (mm == NEGINF) lu = NEGINF;
    else {
      float st = 0.f;
#pragma unroll
      for (int i = 0; i < 8; ++i)
        st += (ms[i][l] == NEGINF) ? 0.f : ss[i][l] * fexp2(ms[i][l] - mm);
      lu = (mm + flog2(st)) * LN2F;
    }
    bool msk = __builtin_isinf(lu);
    float sv = msk ? 0.f : lu;
    float cv = msk ? 0.f : 1.f;
#pragma unroll
    for (int d = 1; d < 64; d <<= 1) { sv += __shfl_xor(sv, d); cv += __shfl_xor(cv, d); }
    if (l == 0) {
      float lf = sv / cv;
      if (hlens[b] < NU) lf = 0.f;
      atomicAdd(out, -lf * (1.0f / NB));
    }
  }
}

// ---------------------------------------------------------------------------
extern "C" void kernel_launch(void* const* d_in, const int* in_sizes, int n_in,
                              void* d_out, int out_size, void* d_ws, size_t ws_size,
                              hipStream_t stream) {
  const float* hs    = (const float*)d_in[0];
  const int*   hlens = (const int*)d_in[1];
  const int*   ys    = (const int*)d_in[2];
  const float* W     = (const float*)d_in[4];
  const float* bias  = (const float*)d_in[5];
  float* out = (float*)d_out;

  char* ws = (char*)d_ws;
  short* hsb   = (short*)(ws + 0);           // 16,384,000 B  live thru k_big
  short* WT    = (short*)(ws + 16384000);    //  5,242,880 B  live thru k_big
  short* WTlo  = (short*)(ws + 21626880);    //  5,242,880 B  dead after k_gather2
  float* ll    = (float*)(ws + 21626880);    //  4,224,000 B  aliases WTlo (k_labg writes)
  float* L     = (float*)(ws + 25850880);    //  2,560,000 B  live thru k_dred
  short* Wg_hi = (short*)(ws + 28410880);    //  1,179,648 B  dead after k_labg
  short* Wg_lo = (short*)(ws + 29590528);    //  1,179,648 B
  float* aod   = (float*)(ws + 28410880);    //  4,096,000 B  aliases Wg (k_big writes)
  float* bpb   = (float*)(ws + 32506880);    //  4,096,000 B
  float* dnm   = (float*)(ws + 36602880);    //     64,000 B  (end 36,666,880)

  k_cvt<<<4640, 256, 0, stream>>>(hs, W, hsb, WT, WTlo, out);
  k_gather2<<<dim3(NWG, 16), 64, 0, stream>>>(WT, WTlo, ys, Wg_hi, Wg_lo);
  k_labg<<<dim3(8, 16), 256, 0, stream>>>(hsb, Wg_hi, Wg_lo, ys, bias, ll);
  k_big<<<5016, 256, 0, stream>>>(hsb, WT, bias, ll, ys, L, aod);
  k_dred<<<63, 256, 0, stream>>>(L, dnm);
  k_bwd<<<NB, 256, 0, stream>>>(ll, dnm, ys, bpb);
  k_loss<<<16, 512, 0, stream>>>(aod, bpb, dnm, hlens, out);
}